// Round 9
// baseline (213.421 us; speedup 1.0000x reference)
//
#include <hip/hip_runtime.h>

constexpr int Bb = 4;
constexpr int Ss = 2048;
constexpr int QSTR = 1536;   // combined qkv row stride (g 0..767, t 768..1535)

typedef __bf16 bf16x8 __attribute__((ext_vector_type(8)));
typedef __bf16 bf16x4 __attribute__((ext_vector_type(4)));
typedef float  f32x4  __attribute__((ext_vector_type(4)));
typedef unsigned int uint2v __attribute__((ext_vector_type(2)));
typedef unsigned int uint4v __attribute__((ext_vector_type(4)));

// async global->LDS, 16B per lane; dest = wave-uniform base + lane*16
__device__ __forceinline__ void glds16(const void* g, void* l) {
    __builtin_amdgcn_global_load_lds(
        (const __attribute__((address_space(1))) unsigned int*)g,
        (__attribute__((address_space(3))) unsigned int*)l, 16, 0, 0);
}

// 4x4 lane-group transpose step across lanes {q, q+16, q+32, q+48}:
// pure VALU: permlane32_swap + permlane16_swap. (Harness-verified in attn.)
__device__ __forceinline__ void xpose4(unsigned int& a, unsigned int& b) {
    uint2v r = __builtin_amdgcn_permlane32_swap(a, b, false, false);
    uint2v u = __builtin_amdgcn_permlane16_swap(r[0], r[1], false, false);
    a = u[0]; b = u[1];
}

// exp2 pair -> packed bf16 in one u32 (bare v_exp_f32 + v_cvt_pk_bf16_f32)
__device__ __forceinline__ unsigned int exp2_pk(float a, float b) {
    float ea = __builtin_amdgcn_exp2f(a);
    float eb = __builtin_amdgcn_exp2f(b);
    unsigned int r;
    asm("v_cvt_pk_bf16_f32 %0, %1, %2" : "=v"(r) : "v"(ea), "v"(eb));
    return r;
}

// ---------------------------------------------------------------------------
// convert_all: fp32 -> bf16 for x and the 8 weight matrices, one launch.
// ---------------------------------------------------------------------------
struct CvtArgs {
    const float* src[9];
    __bf16* dst[9];
    int start[10];
};

__global__ __launch_bounds__(256) void convert_all(CvtArgs a)
{
    int e = 0;
    const int bid = blockIdx.x;
#pragma unroll
    for (int i = 0; i < 8; i++) if (bid >= a.start[i + 1]) e = i + 1;
    const int idx = (bid - a.start[e]) * 256 + threadIdx.x;
    const float* s = a.src[e];
    float4 v0 = *(const float4*)&s[(size_t)idx * 8];
    float4 v1 = *(const float4*)&s[(size_t)idx * 8 + 4];
    bf16x8 o;
    o[0] = (__bf16)v0.x; o[1] = (__bf16)v0.y; o[2] = (__bf16)v0.z; o[3] = (__bf16)v0.w;
    o[4] = (__bf16)v1.x; o[5] = (__bf16)v1.y; o[6] = (__bf16)v1.z; o[7] = (__bf16)v1.w;
    *(bf16x8*)&a.dst[e][(size_t)idx * 8] = o;
}

// ---------------------------------------------------------------------------
// gemm128: BM=BN=128, BK=64; 4 waves each 64x64 (4x4 MFMA accs). For QKV.
// XOR swizzle: LDS slot (row,g) holds global chunk (row, g^(row&7)).
// ---------------------------------------------------------------------------
__global__ __launch_bounds__(256) void gemm128(
    const __bf16* __restrict__ A, const __bf16* __restrict__ W,
    const float* __restrict__ bias, const float* __restrict__ bias2, int bsplit,
    __bf16* __restrict__ C, int K, int ldc)
{
    __shared__ __bf16 As[128 * 64];
    __shared__ __bf16 Ws[128 * 64];
    const int tid = threadIdx.x;
    const int lane = tid & 63;
    const int wv = tid >> 6;
    const int wm = (wv >> 1) * 64;
    const int wn = (wv & 1) * 64;
    const int qrow = lane & 15;
    const int quad = lane >> 4;
    const int n0 = blockIdx.x * 128;
    const int m0 = blockIdx.y * 128;

    f32x4 acc[4][4];
#pragma unroll
    for (int i = 0; i < 4; i++)
#pragma unroll
        for (int j = 0; j < 4; j++) acc[i][j] = {0.f, 0.f, 0.f, 0.f};

    for (int k0 = 0; k0 < K; k0 += 64) {
        __syncthreads();
#pragma unroll
        for (int i = 0; i < 4; i++) {
            const int c = (wv * 4 + i) * 64 + lane;
            const int row = c >> 3, g = c & 7;
            const int gs = (g ^ (row & 7)) * 8;
            glds16(&A[(size_t)(m0 + row) * K + k0 + gs], &As[(wv * 4 + i) * 512]);
            glds16(&W[(size_t)(n0 + row) * K + k0 + gs], &Ws[(wv * 4 + i) * 512]);
        }
        __syncthreads();
#pragma unroll
        for (int ksub = 0; ksub < 2; ksub++) {
            const int gl = ksub * 4 + quad;
            bf16x8 af[4], bf[4];
#pragma unroll
            for (int mi = 0; mi < 4; mi++) {
                const int row = wm + mi * 16 + qrow;
                af[mi] = *(const bf16x8*)&As[row * 64 + (gl ^ (row & 7)) * 8];
            }
#pragma unroll
            for (int ni = 0; ni < 4; ni++) {
                const int row = wn + ni * 16 + qrow;
                bf[ni] = *(const bf16x8*)&Ws[row * 64 + (gl ^ (row & 7)) * 8];
            }
#pragma unroll
            for (int mi = 0; mi < 4; mi++)
#pragma unroll
                for (int ni = 0; ni < 4; ni++)
                    acc[mi][ni] = __builtin_amdgcn_mfma_f32_16x16x32_bf16(
                        af[mi], bf[ni], acc[mi][ni], 0, 0, 0);
        }
    }

    float bz[4];
#pragma unroll
    for (int ni = 0; ni < 4; ni++) {
        const int n = n0 + wn + ni * 16 + qrow;
        bz[ni] = (n < bsplit) ? bias[n] : bias2[n - bsplit];
    }
#pragma unroll
    for (int mi = 0; mi < 4; mi++)
#pragma unroll
        for (int r = 0; r < 4; r++) {
            const int row = m0 + wm + mi * 16 + quad * 4 + r;
#pragma unroll
            for (int ni = 0; ni < 4; ni++) {
                float v = acc[mi][ni][r] + bz[ni];
                C[(size_t)row * ldc + n0 + wn + ni * 16 + qrow] = (__bf16)v;
            }
        }
}

// ---------------------------------------------------------------------------
// gemm_mid: BM=64, BN=64, BK=128; 4 waves as 2(m)x2(n), each 32x32 (2x2 accs).
// Second-weight select: blocks with blockIdx.x >= nsplit use W1/bias1,
// A0+aoff1, coff1. (Verified R4.)
// ---------------------------------------------------------------------------
template<bool SILU, bool OUT_BF16>
__global__ __launch_bounds__(256) void gemm_mid(
    const __bf16* __restrict__ A0, const __bf16* __restrict__ W0,
    const float* __restrict__ bias0, const __bf16* __restrict__ W1,
    const float* __restrict__ bias1, int nsplit, int aoff1, int coff1,
    void* __restrict__ C, int lda, int K, int ldc)
{
    __shared__ __bf16 As[64 * 128];
    __shared__ __bf16 Ws[64 * 128];
    const int tid = threadIdx.x;
    const int lane = tid & 63;
    const int wv = tid >> 6;
    const int wm = (wv >> 1) * 32;
    const int wn = (wv & 1) * 32;
    const int qrow = lane & 15;
    const int quad = lane >> 4;
    const bool second = (int)blockIdx.x >= nsplit;
    const int bx = second ? (blockIdx.x - nsplit) : blockIdx.x;
    const __bf16* A = second ? (A0 + aoff1) : A0;
    const __bf16* W = second ? W1 : W0;
    const float* bias = second ? bias1 : bias0;
    const int coff = second ? coff1 : 0;
    const int n0 = bx * 64;
    const int m0 = blockIdx.y * 64;

    f32x4 acc[2][2];
#pragma unroll
    for (int i = 0; i < 2; i++)
#pragma unroll
        for (int j = 0; j < 2; j++) acc[i][j] = {0.f, 0.f, 0.f, 0.f};

    for (int k0 = 0; k0 < K; k0 += 128) {
        __syncthreads();
#pragma unroll
        for (int i = 0; i < 4; i++) {
            const int c = (wv * 4 + i) * 64 + lane;
            const int row = c >> 4, s = c & 15;
            const int gs = ((s & 8) | ((s ^ row) & 7)) * 8;
            glds16(&A[(size_t)(m0 + row) * lda + k0 + gs], &As[(wv * 4 + i) * 512]);
            glds16(&W[(size_t)(n0 + row) * K + k0 + gs], &Ws[(wv * 4 + i) * 512]);
        }
        __syncthreads();
#pragma unroll
        for (int ksub = 0; ksub < 4; ksub++) {
            const int gl = ksub * 4 + quad;
            bf16x8 af[2], bf[2];
#pragma unroll
            for (int mi = 0; mi < 2; mi++) {
                const int row = wm + mi * 16 + qrow;
                const int s = (gl & 8) | ((gl ^ row) & 7);
                af[mi] = *(const bf16x8*)&As[row * 128 + s * 8];
            }
#pragma unroll
            for (int ni = 0; ni < 2; ni++) {
                const int row = wn + ni * 16 + qrow;
                const int s = (gl & 8) | ((gl ^ row) & 7);
                bf[ni] = *(const bf16x8*)&Ws[row * 128 + s * 8];
            }
#pragma unroll
            for (int mi = 0; mi < 2; mi++)
#pragma unroll
                for (int ni = 0; ni < 2; ni++)
                    acc[mi][ni] = __builtin_amdgcn_mfma_f32_16x16x32_bf16(
                        af[mi], bf[ni], acc[mi][ni], 0, 0, 0);
        }
    }

    float bz[2];
#pragma unroll
    for (int ni = 0; ni < 2; ni++) bz[ni] = bias[n0 + wn + ni * 16 + qrow];

#pragma unroll
    for (int mi = 0; mi < 2; mi++)
#pragma unroll
        for (int r = 0; r < 4; r++) {
            const int row = m0 + wm + mi * 16 + quad * 4 + r;
#pragma unroll
            for (int ni = 0; ni < 2; ni++) {
                float v = acc[mi][ni][r] + bz[ni];
                if (SILU) v = v / (1.f + __expf(-v));
                const int col = coff + n0 + wn + ni * 16 + qrow;
                if (OUT_BF16)
                    ((__bf16*)C)[(size_t)row * ldc + col] = (__bf16)v;
                else
                    ((float*)C)[(size_t)row * ldc + col] = v;
            }
        }
}

// ---------------------------------------------------------------------------
// gemm_out: out-projection with the split-K attention combine FUSED into the
// A-staging. Blocks x<4: A = combined global attention (read 4 Op partials +
// Lp, combine in fp32, cvt bf16, ds_write to the SAME swizzled LDS slot that
// glds16 would fill: chunk c -> &As[c*8]). Blocks x>=4: local half from acat
// cols 256-511 via glds16 (unchanged). Everything after the staging barrier
// is byte-identical to gemm_mid<false,true> (verified). Kernel-launch
// boundary after attn_fused provides cross-XCD coherence for Op/Lp (no
// intra-launch fencing needed). Replaces attn_combine (launch + 4 MB
// write + 4 MB re-read deleted).
// ---------------------------------------------------------------------------
__global__ __launch_bounds__(256) void gemm_out(
    const __bf16* __restrict__ Op, const float* __restrict__ Lp,
    const __bf16* __restrict__ acat,
    const __bf16* __restrict__ w_gout, const float* __restrict__ g_out_b,
    const __bf16* __restrict__ w_tout, const float* __restrict__ t_out_b,
    __bf16* __restrict__ C)
{
    __shared__ __bf16 As[64 * 128];
    __shared__ __bf16 Ws[64 * 128];
    const int tid = threadIdx.x;
    const int lane = tid & 63;
    const int wv = tid >> 6;
    const int wm = (wv >> 1) * 32;
    const int wn = (wv & 1) * 32;
    const int qrow = lane & 15;
    const int quad = lane >> 4;
    const bool second = (int)blockIdx.x >= 4;
    const int bx = second ? (blockIdx.x - 4) : blockIdx.x;
    const __bf16* W = second ? w_tout : w_gout;
    const float* bias = second ? t_out_b : g_out_b;
    const int coff = second ? 256 : 0;
    const int n0 = bx * 64;
    const int m0 = blockIdx.y * 64;

    f32x4 acc[2][2];
#pragma unroll
    for (int i = 0; i < 2; i++)
#pragma unroll
        for (int j = 0; j < 2; j++) acc[i][j] = {0.f, 0.f, 0.f, 0.f};

    for (int k0 = 0; k0 < 256; k0 += 128) {
        __syncthreads();
#pragma unroll
        for (int i = 0; i < 4; i++) {
            const int c = (wv * 4 + i) * 64 + lane;
            const int row = c >> 4, s = c & 15;
            const int gs = ((s & 8) | ((s ^ row) & 7)) * 8;
            if (second) {
                // local half: acat cols 256-511, ld 512
                glds16(&acat[(size_t)(m0 + row) * 512 + 256 + k0 + gs],
                       &As[(wv * 4 + i) * 512]);
            } else {
                // global half: combine 4 split-K partials on the fly
                const int k = k0 + gs;             // feature 0..255
                const int tok = m0 + row;
                const int bq = tok >> 11, q = tok & 2047;
                const int h = k >> 5, d = k & 31;  // d in {0,8,16,24}
                const size_t gid = (size_t)(bq * 8 + h) * 2048 + q;
                const float li = 1.f / (Lp[gid] + Lp[65536 + gid] +
                                        Lp[131072 + gid] + Lp[196608 + gid]);
                const __bf16* base = Op + gid * 32 + d;
                bf16x8 a0 = *(const bf16x8*)&base[0];
                bf16x8 a1 = *(const bf16x8*)&base[2097152];
                bf16x8 a2 = *(const bf16x8*)&base[4194304];
                bf16x8 a3 = *(const bf16x8*)&base[6291456];
                bf16x8 o;
#pragma unroll
                for (int p = 0; p < 8; p++)
                    o[p] = (__bf16)(((float)a0[p] + (float)a1[p] +
                                     (float)a2[p] + (float)a3[p]) * li);
                *(bf16x8*)&As[(size_t)c * 8] = o;
            }
            glds16(&W[(size_t)(n0 + row) * 256 + k0 + gs], &Ws[(wv * 4 + i) * 512]);
        }
        __syncthreads();
#pragma unroll
        for (int ksub = 0; ksub < 4; ksub++) {
            const int gl = ksub * 4 + quad;
            bf16x8 af[2], bf[2];
#pragma unroll
            for (int mi = 0; mi < 2; mi++) {
                const int row = wm + mi * 16 + qrow;
                const int s = (gl & 8) | ((gl ^ row) & 7);
                af[mi] = *(const bf16x8*)&As[row * 128 + s * 8];
            }
#pragma unroll
            for (int ni = 0; ni < 2; ni++) {
                const int row = wn + ni * 16 + qrow;
                const int s = (gl & 8) | ((gl ^ row) & 7);
                bf[ni] = *(const bf16x8*)&Ws[row * 128 + s * 8];
            }
#pragma unroll
            for (int mi = 0; mi < 2; mi++)
#pragma unroll
                for (int ni = 0; ni < 2; ni++)
                    acc[mi][ni] = __builtin_amdgcn_mfma_f32_16x16x32_bf16(
                        af[mi], bf[ni], acc[mi][ni], 0, 0, 0);
        }
    }

    float bz[2];
#pragma unroll
    for (int ni = 0; ni < 2; ni++) bz[ni] = bias[n0 + wn + ni * 16 + qrow];

#pragma unroll
    for (int mi = 0; mi < 2; mi++)
#pragma unroll
        for (int r = 0; r < 4; r++) {
            const int row = m0 + wm + mi * 16 + quad * 4 + r;
#pragma unroll
            for (int ni = 0; ni < 2; ni++) {
                float v = acc[mi][ni][r] + bz[ni];
                const int col = coff + n0 + wn + ni * 16 + qrow;
                C[(size_t)row * 512 + col] = (__bf16)v;
            }
        }
}

// ---------------------------------------------------------------------------
// gemm_ln: full-width GEMM (BM=16 tokens, BN=256 = ALL features, K=512)
// + residual + LayerNorm, fused. (Verified R8.)
// ---------------------------------------------------------------------------
template<bool OBF>
__global__ __launch_bounds__(256) void gemm_ln(
    const __bf16* __restrict__ A, const __bf16* __restrict__ W,
    const float* __restrict__ bias, const float* __restrict__ res,
    const float* __restrict__ g, const float* __restrict__ be,
    float* __restrict__ out, __bf16* __restrict__ outb)
{
    __shared__ __bf16 As[16 * 128];
    __shared__ __bf16 Ws[256 * 128];
    __shared__ float lnp[2][16][4];
    const int tid = threadIdx.x;
    const int lane = tid & 63;
    const int wv = tid >> 6;
    const int qrow = lane & 15;
    const int quad = lane >> 4;
    const int m0 = blockIdx.x * 16;

    f32x4 acc[4];
#pragma unroll
    for (int ni = 0; ni < 4; ni++) acc[ni] = {0.f, 0.f, 0.f, 0.f};

    for (int k0 = 0; k0 < 512; k0 += 128) {
        __syncthreads();
        {
            const int c = wv * 64 + lane;          // 256 chunks = 16 rows x 16
            const int row = c >> 4, s = c & 15;
            const int gs = ((s & 8) | ((s ^ row) & 7)) * 8;
            glds16(&A[(size_t)(m0 + row) * 512 + k0 + gs], &As[wv * 512]);
        }
#pragma unroll
        for (int i = 0; i < 16; i++) {             // 4096 chunks = 256 rows x 16
            const int c = (wv * 16 + i) * 64 + lane;
            const int row = c >> 4, s = c & 15;
            const int gs = ((s & 8) | ((s ^ row) & 7)) * 8;
            glds16(&W[(size_t)row * 512 + k0 + gs], &Ws[(wv * 16 + i) * 512]);
        }
        __syncthreads();
#pragma unroll
        for (int ksub = 0; ksub < 4; ksub++) {
            const int gl = ksub * 4 + quad;
            bf16x8 af, bf[4];
            {
                const int row = qrow;
                const int s = (gl & 8) | ((gl ^ row) & 7);
                af = *(const bf16x8*)&As[row * 128 + s * 8];
            }
#pragma unroll
            for (int ni = 0; ni < 4; ni++) {
                const int row = wv * 64 + ni * 16 + qrow;
                const int s = (gl & 8) | ((gl ^ row) & 7);
                bf[ni] = *(const bf16x8*)&Ws[row * 128 + s * 8];
            }
#pragma unroll
            for (int ni = 0; ni < 4; ni++)
                acc[ni] = __builtin_amdgcn_mfma_f32_16x16x32_bf16(
                    af, bf[ni], acc[ni], 0, 0, 0);
        }
    }

    // d[ni][r] = acc + bias + residual; token = quad*4+r, feature = wv*64+ni*16+qrow
    f32x4 d[4];
#pragma unroll
    for (int ni = 0; ni < 4; ni++) {
        const int f = wv * 64 + ni * 16 + qrow;
        const float bz = bias[f];
#pragma unroll
        for (int r = 0; r < 4; r++)
            d[ni][r] = acc[ni][r] + bz + res[(size_t)(m0 + quad * 4 + r) * 256 + f];
    }

    // LN pass 1: mean. per-lane sum over ni, butterfly over qrow (16 lanes),
    // cross-wave via lnp[0][token][wv].
    f32x4 ps;
#pragma unroll
    for (int r = 0; r < 4; r++) ps[r] = d[0][r] + d[1][r] + d[2][r] + d[3][r];
#pragma unroll
    for (int off = 1; off <= 8; off <<= 1)
#pragma unroll
        for (int r = 0; r < 4; r++) ps[r] += __shfl_xor(ps[r], off, 64);
    if (qrow == 0)
#pragma unroll
        for (int r = 0; r < 4; r++) lnp[0][quad * 4 + r][wv] = ps[r];
    __syncthreads();
    float mu[4];
#pragma unroll
    for (int r = 0; r < 4; r++) {
        const int t = quad * 4 + r;
        mu[r] = (lnp[0][t][0] + lnp[0][t][1] + lnp[0][t][2] + lnp[0][t][3]) * (1.f / 256.f);
    }

    // LN pass 2: variance (two-pass, centered)
#pragma unroll
    for (int r = 0; r < 4; r++) {
        float a0 = d[0][r] - mu[r], a1 = d[1][r] - mu[r];
        float a2 = d[2][r] - mu[r], a3 = d[3][r] - mu[r];
        ps[r] = a0 * a0 + a1 * a1 + a2 * a2 + a3 * a3;
    }
#pragma unroll
    for (int off = 1; off <= 8; off <<= 1)
#pragma unroll
        for (int r = 0; r < 4; r++) ps[r] += __shfl_xor(ps[r], off, 64);
    if (qrow == 0)
#pragma unroll
        for (int r = 0; r < 4; r++) lnp[1][quad * 4 + r][wv] = ps[r];
    __syncthreads();
    float rsv[4];
#pragma unroll
    for (int r = 0; r < 4; r++) {
        const int t = quad * 4 + r;
        float v = (lnp[1][t][0] + lnp[1][t][1] + lnp[1][t][2] + lnp[1][t][3]) * (1.f / 256.f);
        rsv[r] = rsqrtf(v + 1e-5f);
    }

    // write: out = (d - mu) * rs * g + be
#pragma unroll
    for (int ni = 0; ni < 4; ni++) {
        const int f = wv * 64 + ni * 16 + qrow;
        const float gg = g[f];
        const float bb = be[f];
#pragma unroll
        for (int r = 0; r < 4; r++) {
            const size_t idx = (size_t)(m0 + quad * 4 + r) * 256 + f;
            float o = (d[ni][r] - mu[r]) * rsv[r] * gg + bb;
            out[idx] = o;
            if (OBF) outb[idx] = (__bf16)o;
        }
    }
}

// ---------------------------------------------------------------------------
// attn_fused: 512-thread blocks.
// Blocks 0..1023: global MHA split-K x4 partials. 8 waves x 2 q-tiles x 16 q
//   = 256 q/block, 8 key-chunks of 64 keys each. P never touches LDS
//   (permlane transpose). exp2+bf16-pack via v_exp_f32 + v_cvt_pk_bf16_f32.
// Blocks 1024..1535: local window-5 MHA -> acat cols 256-511.
// ---------------------------------------------------------------------------
__global__ __launch_bounds__(512) void attn_fused(
    const __bf16* __restrict__ qkv, __bf16* __restrict__ Op,
    float* __restrict__ Lp, __bf16* __restrict__ acat)
{
    __shared__ __bf16 Kl[2][64 * 32];
    __shared__ __bf16 Vt[2][32 * 72];

    const int t = threadIdx.x;
    const int lane = t & 63;
    const int wv = t >> 6;          // 0..7

    if (blockIdx.x < 1024) {
        const int bid = blockIdx.x;
        const int sp = bid & 3;          // split-K x4
        const int qc = (bid >> 2) & 7;   // 8 chunks of 256 q
        const int h  = (bid >> 5) & 7;
        const int b  = bid >> 8;
        const int bS = b * Ss;
        const int q0 = qc * 256;

        const int qrow = lane & 15;
        const int quad = lane >> 4;
        const float cQ = 1.4426950408889634f * 0.17677669529663687f; // log2e/sqrt(32)

        bf16x8 qf[2];
#pragma unroll
        for (int tl = 0; tl < 2; tl++) {
            bf16x8 qraw = *(const bf16x8*)(qkv +
                (size_t)(bS + q0 + wv * 32 + tl * 16 + qrow) * QSTR + h * 32 + quad * 8);
#pragma unroll
            for (int i = 0; i < 8; i++) qf[tl][i] = (__bf16)((float)qraw[i] * cQ);
        }
        bf16x8 ones;
#pragma unroll
        for (int i = 0; i < 8; i++) ones[i] = (__bf16)1.0f;

        f32x4 o0[2], o1[2], lac[2];
#pragma unroll
        for (int tl = 0; tl < 2; tl++) {
            o0[tl] = {0.f, 0.f, 0.f, 0.f};
            o1[tl] = {0.f, 0.f, 0.f, 0.f};
            lac[tl] = {0.f, 0.f, 0.f, 0.f};
        }
        const f32x4 z = {0.f, 0.f, 0.f, 0.f};

        const int kc_c = wv * 64 + lane;
        const int kkey = kc_c >> 2, kdg = kc_c & 3;
        const int vkey = t & 63, vq = t >> 6;   // V: key, dim group of 4
        const int kc0 = sp * 8;                 // 8 chunks per split

        // prologue: prefetch chunk 0 (V into regs, K via glds into Kl[0])
        bf16x4 vreg = *(const bf16x4*)(qkv +
            (size_t)(bS + kc0 * 64 + vkey) * QSTR + 512 + h * 32 + vq * 4);
        if (wv < 4)
            glds16(qkv + (size_t)(bS + kc0 * 64 + kkey) * QSTR + 256 + h * 32 + kdg * 8,
                   &Kl[0][wv * 512]);

        for (int i = 0; i < 8; i++) {
            const int cur = i & 1;
#pragma unroll
            for (int e = 0; e < 4; e++) Vt[cur][(vq * 4 + e) * 72 + vkey] = vreg[e];
            __syncthreads();
            const int nx = (i < 7) ? (kc0 + i + 1) : (kc0 + 7);
            vreg = *(const bf16x4*)(qkv +
                (size_t)(bS + nx * 64 + vkey) * QSTR + 512 + h * 32 + vq * 4);
            if (i < 7 && wv < 4)
                glds16(qkv + (size_t)(bS + nx * 64 + kkey) * QSTR + 256 + h * 32 + kdg * 8,
                       &Kl[1 - cur][wv * 512]);

            // shared K/V fragments, read once, used by both q-tiles
            bf16x8 kf[4];
#pragma unroll
            for (int kg = 0; kg < 4; kg++)
                kf[kg] = *(const bf16x8*)&Kl[cur][(kg * 16 + qrow) * 32 + quad * 8];
            bf16x8 vf00 = *(const bf16x8*)&Vt[cur][qrow * 72 + quad * 8];
            bf16x8 vf01 = *(const bf16x8*)&Vt[cur][qrow * 72 + 32 + quad * 8];
            bf16x8 vf10 = *(const bf16x8*)&Vt[cur][(16 + qrow) * 72 + quad * 8];
            bf16x8 vf11 = *(const bf16x8*)&Vt[cur][(16 + qrow) * 72 + 32 + quad * 8];

#pragma unroll
            for (int tl = 0; tl < 2; tl++) {
                f32x4 s[4];
#pragma unroll
                for (int kg = 0; kg < 4; kg++)
                    s[kg] = __builtin_amdgcn_mfma_f32_16x16x32_bf16(
                        kf[kg], qf[tl], z, 0, 0, 0);
                unsigned int R[4][2];
#pragma unroll
                for (int kg = 0; kg < 4; kg++) {
                    R[kg][0] = exp2_pk(s[kg][0], s[kg][1]);
                    R[kg][1] = exp2_pk(s[kg][2], s[kg][3]);
                }
                xpose4(R[0][0], R[1][0]);
                xpose4(R[0][1], R[1][1]);
                xpose4(R[2][0], R[3][0]);
                xpose4(R[2][1], R[3][1]);
                uint4v p0u = {R[0][0], R[0][1], R[1][0], R[1][1]};
                uint4v p1u = {R[2][0], R[2][1], R[3][0], R[3][1]};
                bf16x8 pf0 = __builtin_bit_cast(bf16x8, p0u);
                bf16x8 pf1 = __builtin_bit_cast(bf16x8, p1u);

                o0[tl] = __builtin_amdgcn_mfma_f32_16x16x32_bf16(vf00, pf0, o0[tl], 0, 0, 0);
                o1[tl] = __builtin_amdgcn_mfma_f32_16x16x32_bf16(vf10, pf0, o1[tl], 0, 0, 0);
                lac[tl] = __builtin_amdgcn_mfma_f32_16x16x32_bf16(ones, pf0, lac[tl], 0, 0, 0);
                o0[tl] = __builtin_amdgcn_mfma_f32_16x16x32_bf16(vf01, pf1, o0[tl], 0, 0, 0);
                o1[tl] = __builtin_amdgcn_mfma_f32_16x16x32_bf16(vf11, pf1, o1[tl], 0, 0, 0);
                lac[tl] = __builtin_amdgcn_mfma_f32_16x16x32_bf16(ones, pf1, lac[tl], 0, 0, 0);
            }
        }

#pragma unroll
        for (int tl = 0; tl < 2; tl++) {
            const int gid = (b * 8 + h) * 2048 + q0 + wv * 32 + tl * 16 + qrow;
            __bf16* po = Op + (size_t)sp * 2097152 + (size_t)gid * 32;
            bf16x4 w0, w1;
#pragma unroll
            for (int r = 0; r < 4; r++) {
                w0[r] = (__bf16)o0[tl][r];
                w1[r] = (__bf16)o1[tl][r];
            }
            *(bf16x4*)&po[quad * 4]      = w0;
            *(bf16x4*)&po[16 + quad * 4] = w1;
            if (quad == 0) Lp[sp * 65536 + gid] = lac[tl][0];
        }
    } else {
        // local window-5 attention: 8 lanes per (b,s,h) row, 8 rows per wave
        const int w = (blockIdx.x - 1024) * 8 + wv;  // 0..4095
        const int g = lane >> 3;                      // row-in-wave 0..7
        const int l8 = lane & 7;                      // dim-group (8 bf16)
        const int R = w * 8 + g;                      // 0..32767
        const int h = R & 3;
        const int s = (R >> 2) & 2047;
        const int b = R >> 13;

        float qv[8];
        {
            bf16x8 q8 = *(const bf16x8*)&qkv[(size_t)(b * Ss + s) * QSTR + 768 + h * 64 + l8 * 8];
#pragma unroll
            for (int e = 0; e < 8; e++) qv[e] = (float)q8[e];
        }

        float sc[5];
        bf16x8 v8[5];
#pragma unroll
        for (int j = 0; j < 5; j++) {
            int pos = s + j - 2;
            bool valid = (pos >= 0) && (pos < Ss);
            int cpos = valid ? pos : 0;
            const size_t rb = (size_t)(b * Ss + cpos) * QSTR;
            bf16x8 k8 = *(const bf16x8*)&qkv[rb + 1024 + h * 64 + l8 * 8];
            v8[j]     = *(const bf16x8*)&qkv[rb + 1280 + h * 64 + l8 * 8];
            float p = 0.f;
#pragma unroll
            for (int e = 0; e < 8; e++) p += qv[e] * (float)k8[e];
            p += __shfl_xor(p, 1, 64);
            p += __shfl_xor(p, 2, 64);
            p += __shfl_xor(p, 4, 64);
            sc[j] = valid ? p * 0.125f : -1e30f;
        }
        float m = sc[0];
#pragma unroll
        for (int j = 1; j < 5; j++) m = fmaxf(m, sc[j]);
        float l = 0.f;
        float o[8];
#pragma unroll
        for (int e = 0; e < 8; e++) o[e] = 0.f;
#pragma unroll
        for (int j = 0; j < 5; j++) {
            float pe = __builtin_amdgcn_exp2f((sc[j] - m) * 1.4426950408889634f);
            l += pe;
#pragma unroll
            for (int e = 0; e < 8; e++) o[e] += pe * (float)v8[j][e];
        }
        const float li = 1.f / l;
        bf16x8 r;
#pragma unroll
        for (int e = 0; e < 8; e++) r[e] = (__bf16)(o[e] * li);
        *(bf16x8*)&acat[(size_t)(b * Ss + s) * 512 + 256 + h * 64 + l8 * 8] = r;
    }
}

// ---------------------------------------------------------------------------
extern "C" void kernel_launch(void* const* d_in, const int* in_sizes, int n_in,
                              void* d_out, int out_size, void* d_ws, size_t ws_size,
                              hipStream_t stream)
{
    const float* x      = (const float*)d_in[0];
    const float* g_in_w = (const float*)d_in[1];
    const float* g_in_b = (const float*)d_in[2];
    const float* g_out_w= (const float*)d_in[3];
    const float* g_out_b= (const float*)d_in[4];
    const float* t_in_w = (const float*)d_in[5];
    const float* t_in_b = (const float*)d_in[6];
    const float* t_out_w= (const float*)d_in[7];
    const float* t_out_b= (const float*)d_in[8];
    const float* fus_w1 = (const float*)d_in[9];
    const float* fus_b1 = (const float*)d_in[10];
    const float* fus_w2 = (const float*)d_in[11];
    const float* fus_b2 = (const float*)d_in[12];
    const float* ffn_w1 = (const float*)d_in[13];
    const float* ffn_b1 = (const float*)d_in[14];
    const float* ffn_w2 = (const float*)d_in[15];
    const float* ffn_b2 = (const float*)d_in[16];
    const float* gn_g   = (const float*)d_in[17];
    const float* gn_b   = (const float*)d_in[18];
    const float* fn_g   = (const float*)d_in[19];
    const float* fn_b   = (const float*)d_in[20];
    float* out = (float*)d_out;
    float* ws  = (float*)d_ws;

    // ws layout in f32 slots
    __bf16* xb     = (__bf16*)(ws);                 // [0, 1048576)
    __bf16* wb     = (__bf16*)(ws + 1048576);       // [1048576, 1638400)
    __bf16* qkvgl  = (__bf16*)(ws + 1638400);       // [1638400, 7929856)  8192x1536
    __bf16* acat   = (__bf16*)(ws + 7929856);       // [7929856, 10027008) 8192x512
    __bf16* fcomb  = (__bf16*)(ws + 10027008);      // [10027008, 12124160) 8192x512
    __bf16* h1     = (__bf16*)(ws + 12124160);      // [12124160, 14221312) 8192x512
    // Op moved OUT of fcomb's slot: gemm_out reads Op while writing fcomb.
    // Op lifetime (attn_fused -> gemm_out) is disjoint from x2 (ln1 -> ln2).
    __bf16* Op = (__bf16*)(ws + 14221312);          // [14221312, 18415616) 4x65536x32 bf16
    float*  x2     = ws + 16318464;                 // [16318464, 18415616) fp32 (after Op dead)
    float*  Lp = ws + 18415616;                     // [18415616, 18677760) 4x65536 fp32
    __bf16* x2b    = (__bf16*)(ws + 18415616);      // [18415616, 19464192) (after Lp dead)
    __bf16* h2     = h1;                            // reuse

    __bf16* w_gin  = wb;              // [1536x256] combined (g rows 0-767, t 768-1535)
    __bf16* w_gout = wb + 393216;
    __bf16* w_tout = wb + 458752;
    __bf16* w_f1   = wb + 524288;
    __bf16* w_f2   = wb + 786432;
    __bf16* w_n1   = wb + 917504;
    __bf16* w_n2   = wb + 1048576;

    CvtArgs ca;
    ca.src[0] = x;      ca.dst[0] = xb;
    ca.src[1] = g_in_w; ca.dst[1] = w_gin;
    ca.src[2] = t_in_w; ca.dst[2] = w_gin + 196608;
    ca.src[3] = g_out_w;ca.dst[3] = w_gout;
    ca.src[4] = t_out_w;ca.dst[4] = w_tout;
    ca.src[5] = fus_w1; ca.dst[5] = w_f1;
    ca.src[6] = fus_w2; ca.dst[6] = w_f2;
    ca.src[7] = ffn_w1; ca.dst[7] = w_n1;
    ca.src[8] = ffn_w2; ca.dst[8] = w_n2;
    int st[10] = {0, 1024, 1120, 1216, 1248, 1280, 1408, 1472, 1536, 1600};
    for (int i = 0; i < 10; i++) ca.start[i] = st[i];

    convert_all<<<dim3(1600), 256, 0, stream>>>(ca);

    // Combined QKV projection: M=8192, N=1536, K=256 -> qkvgl (128x128 tiles)
    gemm128<<<dim3(12, 64), 256, 0, stream>>>(
        xb, w_gin, g_in_b, t_in_b, 768, qkvgl, 256, QSTR);
    // Global attention partials split-K x4 (blocks 0-1023) + local (1024-1535)
    attn_fused<<<dim3(1536), 512, 0, stream>>>(qkvgl, Op, Lp, acat);
    // Out-projection with fused split-K combine (global half reads Op/Lp)
    gemm_out<<<dim3(8, 128), 256, 0, stream>>>(
        Op, Lp, acat, w_gout, g_out_b, w_tout, t_out_b, fcomb);
    // Fusion MLP layer 1
    gemm_mid<true,  true><<<dim3(8, 128), 256, 0, stream>>>(
        fcomb, w_f1, fus_b1, w_f1, fus_b1, 1 << 30, 0, 0, h1, 512, 512, 512);
    // Fusion MLP layer 2 + residual(x) + LN1 -> x2 (fp32) and x2b (bf16)
    gemm_ln<true><<<dim3(512), 256, 0, stream>>>(
        h1, w_f2, fus_b2, x, gn_g, gn_b, x2, x2b);
    // FFN layer 1
    gemm_mid<true,  true><<<dim3(8, 128), 256, 0, stream>>>(
        x2b, w_n1, ffn_b1, w_n1, ffn_b1, 1 << 30, 0, 0, h2, 256, 256, 512);
    // FFN layer 2 + residual(x2) + LN2 -> out
    gemm_ln<false><<<dim3(512), 256, 0, stream>>>(
        h2, w_n2, ffn_b2, x2, fn_g, fn_b, out, nullptr);
}

// Round 10
// 205.319 us; speedup vs baseline: 1.0395x; 1.0395x over previous
//
#include <hip/hip_runtime.h>

constexpr int Bb = 4;
constexpr int Ss = 2048;
constexpr int QSTR = 1536;   // combined qkv row stride (g 0..767, t 768..1535)

typedef __bf16 bf16x8 __attribute__((ext_vector_type(8)));
typedef __bf16 bf16x4 __attribute__((ext_vector_type(4)));
typedef float  f32x4  __attribute__((ext_vector_type(4)));
typedef unsigned int uint2v __attribute__((ext_vector_type(2)));
typedef unsigned int uint4v __attribute__((ext_vector_type(4)));

// async global->LDS, 16B per lane; dest = wave-uniform base + lane*16
__device__ __forceinline__ void glds16(const void* g, void* l) {
    __builtin_amdgcn_global_load_lds(
        (const __attribute__((address_space(1))) unsigned int*)g,
        (__attribute__((address_space(3))) unsigned int*)l, 16, 0, 0);
}

// 4x4 lane-group transpose step across lanes {q, q+16, q+32, q+48}:
// pure VALU: permlane32_swap + permlane16_swap. (Harness-verified in attn.)
__device__ __forceinline__ void xpose4(unsigned int& a, unsigned int& b) {
    uint2v r = __builtin_amdgcn_permlane32_swap(a, b, false, false);
    uint2v u = __builtin_amdgcn_permlane16_swap(r[0], r[1], false, false);
    a = u[0]; b = u[1];
}

// exp2 pair -> packed bf16 in one u32 (bare v_exp_f32 + v_cvt_pk_bf16_f32)
__device__ __forceinline__ unsigned int exp2_pk(float a, float b) {
    float ea = __builtin_amdgcn_exp2f(a);
    float eb = __builtin_amdgcn_exp2f(b);
    unsigned int r;
    asm("v_cvt_pk_bf16_f32 %0, %1, %2" : "=v"(r) : "v"(ea), "v"(eb));
    return r;
}

// fast silu: v / (1 + 2^(-v*log2e)) — bare v_exp_f32, verified R5-R7 numerics
__device__ __forceinline__ float silu_fast(float v) {
    return v / (1.f + __builtin_amdgcn_exp2f(-v * 1.4426950408889634f));
}

// ---------------------------------------------------------------------------
// convert_all: fp32 -> bf16 for x and the 8 weight matrices, one launch.
// ---------------------------------------------------------------------------
struct CvtArgs {
    const float* src[9];
    __bf16* dst[9];
    int start[10];
};

__global__ __launch_bounds__(256) void convert_all(CvtArgs a)
{
    int e = 0;
    const int bid = blockIdx.x;
#pragma unroll
    for (int i = 0; i < 8; i++) if (bid >= a.start[i + 1]) e = i + 1;
    const int idx = (bid - a.start[e]) * 256 + threadIdx.x;
    const float* s = a.src[e];
    float4 v0 = *(const float4*)&s[(size_t)idx * 8];
    float4 v1 = *(const float4*)&s[(size_t)idx * 8 + 4];
    bf16x8 o;
    o[0] = (__bf16)v0.x; o[1] = (__bf16)v0.y; o[2] = (__bf16)v0.z; o[3] = (__bf16)v0.w;
    o[4] = (__bf16)v1.x; o[5] = (__bf16)v1.y; o[6] = (__bf16)v1.z; o[7] = (__bf16)v1.w;
    *(bf16x8*)&a.dst[e][(size_t)idx * 8] = o;
}

// ---------------------------------------------------------------------------
// gemm128: BM=BN=128, BK=64; 4 waves each 64x64 (4x4 MFMA accs). For QKV.
// XOR swizzle: LDS slot (row,g) holds global chunk (row, g^(row&7)).
// ---------------------------------------------------------------------------
__global__ __launch_bounds__(256) void gemm128(
    const __bf16* __restrict__ A, const __bf16* __restrict__ W,
    const float* __restrict__ bias, const float* __restrict__ bias2, int bsplit,
    __bf16* __restrict__ C, int K, int ldc)
{
    __shared__ __bf16 As[128 * 64];
    __shared__ __bf16 Ws[128 * 64];
    const int tid = threadIdx.x;
    const int lane = tid & 63;
    const int wv = tid >> 6;
    const int wm = (wv >> 1) * 64;
    const int wn = (wv & 1) * 64;
    const int qrow = lane & 15;
    const int quad = lane >> 4;
    const int n0 = blockIdx.x * 128;
    const int m0 = blockIdx.y * 128;

    f32x4 acc[4][4];
#pragma unroll
    for (int i = 0; i < 4; i++)
#pragma unroll
        for (int j = 0; j < 4; j++) acc[i][j] = {0.f, 0.f, 0.f, 0.f};

    for (int k0 = 0; k0 < K; k0 += 64) {
        __syncthreads();
#pragma unroll
        for (int i = 0; i < 4; i++) {
            const int c = (wv * 4 + i) * 64 + lane;
            const int row = c >> 3, g = c & 7;
            const int gs = (g ^ (row & 7)) * 8;
            glds16(&A[(size_t)(m0 + row) * K + k0 + gs], &As[(wv * 4 + i) * 512]);
            glds16(&W[(size_t)(n0 + row) * K + k0 + gs], &Ws[(wv * 4 + i) * 512]);
        }
        __syncthreads();
#pragma unroll
        for (int ksub = 0; ksub < 2; ksub++) {
            const int gl = ksub * 4 + quad;
            bf16x8 af[4], bf[4];
#pragma unroll
            for (int mi = 0; mi < 4; mi++) {
                const int row = wm + mi * 16 + qrow;
                af[mi] = *(const bf16x8*)&As[row * 64 + (gl ^ (row & 7)) * 8];
            }
#pragma unroll
            for (int ni = 0; ni < 4; ni++) {
                const int row = wn + ni * 16 + qrow;
                bf[ni] = *(const bf16x8*)&Ws[row * 64 + (gl ^ (row & 7)) * 8];
            }
#pragma unroll
            for (int mi = 0; mi < 4; mi++)
#pragma unroll
                for (int ni = 0; ni < 4; ni++)
                    acc[mi][ni] = __builtin_amdgcn_mfma_f32_16x16x32_bf16(
                        af[mi], bf[ni], acc[mi][ni], 0, 0, 0);
        }
    }

    float bz[4];
#pragma unroll
    for (int ni = 0; ni < 4; ni++) {
        const int n = n0 + wn + ni * 16 + qrow;
        bz[ni] = (n < bsplit) ? bias[n] : bias2[n - bsplit];
    }
#pragma unroll
    for (int mi = 0; mi < 4; mi++)
#pragma unroll
        for (int r = 0; r < 4; r++) {
            const int row = m0 + wm + mi * 16 + quad * 4 + r;
#pragma unroll
            for (int ni = 0; ni < 4; ni++) {
                float v = acc[mi][ni][r] + bz[ni];
                C[(size_t)row * ldc + n0 + wn + ni * 16 + qrow] = (__bf16)v;
            }
        }
}

// ---------------------------------------------------------------------------
// gemm_mid: BM=64, BN=64, BK=128; 4 waves as 2(m)x2(n), each 32x32 (2x2 accs).
// Second-weight select: blocks with blockIdx.x >= nsplit use W1/bias1,
// A0+aoff1, coff1. (Verified R4; SILU switched to bare-v_exp form, verified
// numerics in R5-R7 stage_pack4.)
// ---------------------------------------------------------------------------
template<bool SILU, bool OUT_BF16>
__global__ __launch_bounds__(256) void gemm_mid(
    const __bf16* __restrict__ A0, const __bf16* __restrict__ W0,
    const float* __restrict__ bias0, const __bf16* __restrict__ W1,
    const float* __restrict__ bias1, int nsplit, int aoff1, int coff1,
    void* __restrict__ C, int lda, int K, int ldc)
{
    __shared__ __bf16 As[64 * 128];
    __shared__ __bf16 Ws[64 * 128];
    const int tid = threadIdx.x;
    const int lane = tid & 63;
    const int wv = tid >> 6;
    const int wm = (wv >> 1) * 32;
    const int wn = (wv & 1) * 32;
    const int qrow = lane & 15;
    const int quad = lane >> 4;
    const bool second = (int)blockIdx.x >= nsplit;
    const int bx = second ? (blockIdx.x - nsplit) : blockIdx.x;
    const __bf16* A = second ? (A0 + aoff1) : A0;
    const __bf16* W = second ? W1 : W0;
    const float* bias = second ? bias1 : bias0;
    const int coff = second ? coff1 : 0;
    const int n0 = bx * 64;
    const int m0 = blockIdx.y * 64;

    f32x4 acc[2][2];
#pragma unroll
    for (int i = 0; i < 2; i++)
#pragma unroll
        for (int j = 0; j < 2; j++) acc[i][j] = {0.f, 0.f, 0.f, 0.f};

    for (int k0 = 0; k0 < K; k0 += 128) {
        __syncthreads();
#pragma unroll
        for (int i = 0; i < 4; i++) {
            const int c = (wv * 4 + i) * 64 + lane;
            const int row = c >> 4, s = c & 15;
            const int gs = ((s & 8) | ((s ^ row) & 7)) * 8;
            glds16(&A[(size_t)(m0 + row) * lda + k0 + gs], &As[(wv * 4 + i) * 512]);
            glds16(&W[(size_t)(n0 + row) * K + k0 + gs], &Ws[(wv * 4 + i) * 512]);
        }
        __syncthreads();
#pragma unroll
        for (int ksub = 0; ksub < 4; ksub++) {
            const int gl = ksub * 4 + quad;
            bf16x8 af[2], bf[2];
#pragma unroll
            for (int mi = 0; mi < 2; mi++) {
                const int row = wm + mi * 16 + qrow;
                const int s = (gl & 8) | ((gl ^ row) & 7);
                af[mi] = *(const bf16x8*)&As[row * 128 + s * 8];
            }
#pragma unroll
            for (int ni = 0; ni < 2; ni++) {
                const int row = wn + ni * 16 + qrow;
                const int s = (gl & 8) | ((gl ^ row) & 7);
                bf[ni] = *(const bf16x8*)&Ws[row * 128 + s * 8];
            }
#pragma unroll
            for (int mi = 0; mi < 2; mi++)
#pragma unroll
                for (int ni = 0; ni < 2; ni++)
                    acc[mi][ni] = __builtin_amdgcn_mfma_f32_16x16x32_bf16(
                        af[mi], bf[ni], acc[mi][ni], 0, 0, 0);
        }
    }

    float bz[2];
#pragma unroll
    for (int ni = 0; ni < 2; ni++) bz[ni] = bias[n0 + wn + ni * 16 + qrow];

#pragma unroll
    for (int mi = 0; mi < 2; mi++)
#pragma unroll
        for (int r = 0; r < 4; r++) {
            const int row = m0 + wm + mi * 16 + quad * 4 + r;
#pragma unroll
            for (int ni = 0; ni < 2; ni++) {
                float v = acc[mi][ni][r] + bz[ni];
                if (SILU) v = silu_fast(v);
                const int col = coff + n0 + wn + ni * 16 + qrow;
                if (OUT_BF16)
                    ((__bf16*)C)[(size_t)row * ldc + col] = (__bf16)v;
                else
                    ((float*)C)[(size_t)row * ldc + col] = v;
            }
        }
}

// ---------------------------------------------------------------------------
// gemm_ln: full-width GEMM (BM=16 tokens, BN=256 = ALL features, K=512)
// + residual + LayerNorm, fused. (Verified R8.)
// ---------------------------------------------------------------------------
template<bool OBF>
__global__ __launch_bounds__(256) void gemm_ln(
    const __bf16* __restrict__ A, const __bf16* __restrict__ W,
    const float* __restrict__ bias, const float* __restrict__ res,
    const float* __restrict__ g, const float* __restrict__ be,
    float* __restrict__ out, __bf16* __restrict__ outb)
{
    __shared__ __bf16 As[16 * 128];
    __shared__ __bf16 Ws[256 * 128];
    __shared__ float lnp[2][16][4];
    const int tid = threadIdx.x;
    const int lane = tid & 63;
    const int wv = tid >> 6;
    const int qrow = lane & 15;
    const int quad = lane >> 4;
    const int m0 = blockIdx.x * 16;

    f32x4 acc[4];
#pragma unroll
    for (int ni = 0; ni < 4; ni++) acc[ni] = {0.f, 0.f, 0.f, 0.f};

    for (int k0 = 0; k0 < 512; k0 += 128) {
        __syncthreads();
        {
            const int c = wv * 64 + lane;          // 256 chunks = 16 rows x 16
            const int row = c >> 4, s = c & 15;
            const int gs = ((s & 8) | ((s ^ row) & 7)) * 8;
            glds16(&A[(size_t)(m0 + row) * 512 + k0 + gs], &As[wv * 512]);
        }
#pragma unroll
        for (int i = 0; i < 16; i++) {             // 4096 chunks = 256 rows x 16
            const int c = (wv * 16 + i) * 64 + lane;
            const int row = c >> 4, s = c & 15;
            const int gs = ((s & 8) | ((s ^ row) & 7)) * 8;
            glds16(&W[(size_t)row * 512 + k0 + gs], &Ws[(wv * 16 + i) * 512]);
        }
        __syncthreads();
#pragma unroll
        for (int ksub = 0; ksub < 4; ksub++) {
            const int gl = ksub * 4 + quad;
            bf16x8 af, bf[4];
            {
                const int row = qrow;
                const int s = (gl & 8) | ((gl ^ row) & 7);
                af = *(const bf16x8*)&As[row * 128 + s * 8];
            }
#pragma unroll
            for (int ni = 0; ni < 4; ni++) {
                const int row = wv * 64 + ni * 16 + qrow;
                const int s = (gl & 8) | ((gl ^ row) & 7);
                bf[ni] = *(const bf16x8*)&Ws[row * 128 + s * 8];
            }
#pragma unroll
            for (int ni = 0; ni < 4; ni++)
                acc[ni] = __builtin_amdgcn_mfma_f32_16x16x32_bf16(
                    af, bf[ni], acc[ni], 0, 0, 0);
        }
    }

    // d[ni][r] = acc + bias + residual; token = quad*4+r, feature = wv*64+ni*16+qrow
    f32x4 d[4];
#pragma unroll
    for (int ni = 0; ni < 4; ni++) {
        const int f = wv * 64 + ni * 16 + qrow;
        const float bz = bias[f];
#pragma unroll
        for (int r = 0; r < 4; r++)
            d[ni][r] = acc[ni][r] + bz + res[(size_t)(m0 + quad * 4 + r) * 256 + f];
    }

    // LN pass 1: mean. per-lane sum over ni, butterfly over qrow (16 lanes),
    // cross-wave via lnp[0][token][wv].
    f32x4 ps;
#pragma unroll
    for (int r = 0; r < 4; r++) ps[r] = d[0][r] + d[1][r] + d[2][r] + d[3][r];
#pragma unroll
    for (int off = 1; off <= 8; off <<= 1)
#pragma unroll
        for (int r = 0; r < 4; r++) ps[r] += __shfl_xor(ps[r], off, 64);
    if (qrow == 0)
#pragma unroll
        for (int r = 0; r < 4; r++) lnp[0][quad * 4 + r][wv] = ps[r];
    __syncthreads();
    float mu[4];
#pragma unroll
    for (int r = 0; r < 4; r++) {
        const int t = quad * 4 + r;
        mu[r] = (lnp[0][t][0] + lnp[0][t][1] + lnp[0][t][2] + lnp[0][t][3]) * (1.f / 256.f);
    }

    // LN pass 2: variance (two-pass, centered)
#pragma unroll
    for (int r = 0; r < 4; r++) {
        float a0 = d[0][r] - mu[r], a1 = d[1][r] - mu[r];
        float a2 = d[2][r] - mu[r], a3 = d[3][r] - mu[r];
        ps[r] = a0 * a0 + a1 * a1 + a2 * a2 + a3 * a3;
    }
#pragma unroll
    for (int off = 1; off <= 8; off <<= 1)
#pragma unroll
        for (int r = 0; r < 4; r++) ps[r] += __shfl_xor(ps[r], off, 64);
    if (qrow == 0)
#pragma unroll
        for (int r = 0; r < 4; r++) lnp[1][quad * 4 + r][wv] = ps[r];
    __syncthreads();
    float rsv[4];
#pragma unroll
    for (int r = 0; r < 4; r++) {
        const int t = quad * 4 + r;
        float v = (lnp[1][t][0] + lnp[1][t][1] + lnp[1][t][2] + lnp[1][t][3]) * (1.f / 256.f);
        rsv[r] = rsqrtf(v + 1e-5f);
    }

    // write: out = (d - mu) * rs * g + be
#pragma unroll
    for (int ni = 0; ni < 4; ni++) {
        const int f = wv * 64 + ni * 16 + qrow;
        const float gg = g[f];
        const float bb = be[f];
#pragma unroll
        for (int r = 0; r < 4; r++) {
            const size_t idx = (size_t)(m0 + quad * 4 + r) * 256 + f;
            float o = (d[ni][r] - mu[r]) * rsv[r] * gg + bb;
            out[idx] = o;
            if (OBF) outb[idx] = (__bf16)o;
        }
    }
}

// ---------------------------------------------------------------------------
// attn_fused: 512-thread blocks.
// Blocks 0..1023: global MHA split-K x4 partials. 8 waves x 2 q-tiles x 16 q
//   = 256 q/block, 8 key-chunks of 64 keys each. P never touches LDS
//   (permlane transpose). exp2+bf16-pack via v_exp_f32 + v_cvt_pk_bf16_f32.
// Blocks 1024..1535: local window-5 MHA -> acat cols 256-511.
// ---------------------------------------------------------------------------
__global__ __launch_bounds__(512) void attn_fused(
    const __bf16* __restrict__ qkv, __bf16* __restrict__ Op,
    float* __restrict__ Lp, __bf16* __restrict__ acat)
{
    __shared__ __bf16 Kl[2][64 * 32];
    __shared__ __bf16 Vt[2][32 * 72];

    const int t = threadIdx.x;
    const int lane = t & 63;
    const int wv = t >> 6;          // 0..7

    if (blockIdx.x < 1024) {
        const int bid = blockIdx.x;
        const int sp = bid & 3;          // split-K x4
        const int qc = (bid >> 2) & 7;   // 8 chunks of 256 q
        const int h  = (bid >> 5) & 7;
        const int b  = bid >> 8;
        const int bS = b * Ss;
        const int q0 = qc * 256;

        const int qrow = lane & 15;
        const int quad = lane >> 4;
        const float cQ = 1.4426950408889634f * 0.17677669529663687f; // log2e/sqrt(32)

        bf16x8 qf[2];
#pragma unroll
        for (int tl = 0; tl < 2; tl++) {
            bf16x8 qraw = *(const bf16x8*)(qkv +
                (size_t)(bS + q0 + wv * 32 + tl * 16 + qrow) * QSTR + h * 32 + quad * 8);
#pragma unroll
            for (int i = 0; i < 8; i++) qf[tl][i] = (__bf16)((float)qraw[i] * cQ);
        }
        bf16x8 ones;
#pragma unroll
        for (int i = 0; i < 8; i++) ones[i] = (__bf16)1.0f;

        f32x4 o0[2], o1[2], lac[2];
#pragma unroll
        for (int tl = 0; tl < 2; tl++) {
            o0[tl] = {0.f, 0.f, 0.f, 0.f};
            o1[tl] = {0.f, 0.f, 0.f, 0.f};
            lac[tl] = {0.f, 0.f, 0.f, 0.f};
        }
        const f32x4 z = {0.f, 0.f, 0.f, 0.f};

        const int kc_c = wv * 64 + lane;
        const int kkey = kc_c >> 2, kdg = kc_c & 3;
        const int vkey = t & 63, vq = t >> 6;   // V: key, dim group of 4
        const int kc0 = sp * 8;                 // 8 chunks per split

        // prologue: prefetch chunk 0 (V into regs, K via glds into Kl[0])
        bf16x4 vreg = *(const bf16x4*)(qkv +
            (size_t)(bS + kc0 * 64 + vkey) * QSTR + 512 + h * 32 + vq * 4);
        if (wv < 4)
            glds16(qkv + (size_t)(bS + kc0 * 64 + kkey) * QSTR + 256 + h * 32 + kdg * 8,
                   &Kl[0][wv * 512]);

        for (int i = 0; i < 8; i++) {
            const int cur = i & 1;
#pragma unroll
            for (int e = 0; e < 4; e++) Vt[cur][(vq * 4 + e) * 72 + vkey] = vreg[e];
            __syncthreads();
            const int nx = (i < 7) ? (kc0 + i + 1) : (kc0 + 7);
            vreg = *(const bf16x4*)(qkv +
                (size_t)(bS + nx * 64 + vkey) * QSTR + 512 + h * 32 + vq * 4);
            if (i < 7 && wv < 4)
                glds16(qkv + (size_t)(bS + nx * 64 + kkey) * QSTR + 256 + h * 32 + kdg * 8,
                       &Kl[1 - cur][wv * 512]);

            // shared K/V fragments, read once, used by both q-tiles
            bf16x8 kf[4];
#pragma unroll
            for (int kg = 0; kg < 4; kg++)
                kf[kg] = *(const bf16x8*)&Kl[cur][(kg * 16 + qrow) * 32 + quad * 8];
            bf16x8 vf00 = *(const bf16x8*)&Vt[cur][qrow * 72 + quad * 8];
            bf16x8 vf01 = *(const bf16x8*)&Vt[cur][qrow * 72 + 32 + quad * 8];
            bf16x8 vf10 = *(const bf16x8*)&Vt[cur][(16 + qrow) * 72 + quad * 8];
            bf16x8 vf11 = *(const bf16x8*)&Vt[cur][(16 + qrow) * 72 + 32 + quad * 8];

#pragma unroll
            for (int tl = 0; tl < 2; tl++) {
                f32x4 s[4];
#pragma unroll
                for (int kg = 0; kg < 4; kg++)
                    s[kg] = __builtin_amdgcn_mfma_f32_16x16x32_bf16(
                        kf[kg], qf[tl], z, 0, 0, 0);
                unsigned int R[4][2];
#pragma unroll
                for (int kg = 0; kg < 4; kg++) {
                    R[kg][0] = exp2_pk(s[kg][0], s[kg][1]);
                    R[kg][1] = exp2_pk(s[kg][2], s[kg][3]);
                }
                xpose4(R[0][0], R[1][0]);
                xpose4(R[0][1], R[1][1]);
                xpose4(R[2][0], R[3][0]);
                xpose4(R[2][1], R[3][1]);
                uint4v p0u = {R[0][0], R[0][1], R[1][0], R[1][1]};
                uint4v p1u = {R[2][0], R[2][1], R[3][0], R[3][1]};
                bf16x8 pf0 = __builtin_bit_cast(bf16x8, p0u);
                bf16x8 pf1 = __builtin_bit_cast(bf16x8, p1u);

                o0[tl] = __builtin_amdgcn_mfma_f32_16x16x32_bf16(vf00, pf0, o0[tl], 0, 0, 0);
                o1[tl] = __builtin_amdgcn_mfma_f32_16x16x32_bf16(vf10, pf0, o1[tl], 0, 0, 0);
                lac[tl] = __builtin_amdgcn_mfma_f32_16x16x32_bf16(ones, pf0, lac[tl], 0, 0, 0);
                o0[tl] = __builtin_amdgcn_mfma_f32_16x16x32_bf16(vf01, pf1, o0[tl], 0, 0, 0);
                o1[tl] = __builtin_amdgcn_mfma_f32_16x16x32_bf16(vf11, pf1, o1[tl], 0, 0, 0);
                lac[tl] = __builtin_amdgcn_mfma_f32_16x16x32_bf16(ones, pf1, lac[tl], 0, 0, 0);
            }
        }

#pragma unroll
        for (int tl = 0; tl < 2; tl++) {
            const int gid = (b * 8 + h) * 2048 + q0 + wv * 32 + tl * 16 + qrow;
            __bf16* po = Op + (size_t)sp * 2097152 + (size_t)gid * 32;
            bf16x4 w0, w1;
#pragma unroll
            for (int r = 0; r < 4; r++) {
                w0[r] = (__bf16)o0[tl][r];
                w1[r] = (__bf16)o1[tl][r];
            }
            *(bf16x4*)&po[quad * 4]      = w0;
            *(bf16x4*)&po[16 + quad * 4] = w1;
            if (quad == 0) Lp[sp * 65536 + gid] = lac[tl][0];
        }
    } else {
        // local window-5 attention: 8 lanes per (b,s,h) row, 8 rows per wave
        const int w = (blockIdx.x - 1024) * 8 + wv;  // 0..4095
        const int g = lane >> 3;                      // row-in-wave 0..7
        const int l8 = lane & 7;                      // dim-group (8 bf16)
        const int R = w * 8 + g;                      // 0..32767
        const int h = R & 3;
        const int s = (R >> 2) & 2047;
        const int b = R >> 13;

        float qv[8];
        {
            bf16x8 q8 = *(const bf16x8*)&qkv[(size_t)(b * Ss + s) * QSTR + 768 + h * 64 + l8 * 8];
#pragma unroll
            for (int e = 0; e < 8; e++) qv[e] = (float)q8[e];
        }

        float sc[5];
        bf16x8 v8[5];
#pragma unroll
        for (int j = 0; j < 5; j++) {
            int pos = s + j - 2;
            bool valid = (pos >= 0) && (pos < Ss);
            int cpos = valid ? pos : 0;
            const size_t rb = (size_t)(b * Ss + cpos) * QSTR;
            bf16x8 k8 = *(const bf16x8*)&qkv[rb + 1024 + h * 64 + l8 * 8];
            v8[j]     = *(const bf16x8*)&qkv[rb + 1280 + h * 64 + l8 * 8];
            float p = 0.f;
#pragma unroll
            for (int e = 0; e < 8; e++) p += qv[e] * (float)k8[e];
            p += __shfl_xor(p, 1, 64);
            p += __shfl_xor(p, 2, 64);
            p += __shfl_xor(p, 4, 64);
            sc[j] = valid ? p * 0.125f : -1e30f;
        }
        float m = sc[0];
#pragma unroll
        for (int j = 1; j < 5; j++) m = fmaxf(m, sc[j]);
        float l = 0.f;
        float o[8];
#pragma unroll
        for (int e = 0; e < 8; e++) o[e] = 0.f;
#pragma unroll
        for (int j = 0; j < 5; j++) {
            float pe = __builtin_amdgcn_exp2f((sc[j] - m) * 1.4426950408889634f);
            l += pe;
#pragma unroll
            for (int e = 0; e < 8; e++) o[e] += pe * (float)v8[j][e];
        }
        const float li = 1.f / l;
        bf16x8 r;
#pragma unroll
        for (int e = 0; e < 8; e++) r[e] = (__bf16)(o[e] * li);
        *(bf16x8*)&acat[(size_t)(b * Ss + s) * 512 + 256 + h * 64 + l8 * 8] = r;
    }
}

// ---------------------------------------------------------------------------
// attn_combine: 4 bf16 split partials -> acat cols 0-255. (Verified R3-R8.)
// ---------------------------------------------------------------------------
__global__ __launch_bounds__(256) void attn_combine(
    const __bf16* __restrict__ Op, const float* __restrict__ Lp,
    __bf16* __restrict__ acat)
{
    const int t = blockIdx.x * 256 + threadIdx.x;   // 0 .. 524287
    const int gid = t >> 3;
    const int dg = t & 7;
    const int b = gid >> 14;
    const int h = (gid >> 11) & 7;
    const int q = gid & 2047;

    const float li = 1.f / (Lp[gid] + Lp[65536 + gid] +
                            Lp[131072 + gid] + Lp[196608 + gid]);
    const __bf16* base = Op + (size_t)gid * 32 + dg * 4;
    bf16x4 a0 = *(const bf16x4*)&base[0];
    bf16x4 a1 = *(const bf16x4*)&base[2097152];
    bf16x4 a2 = *(const bf16x4*)&base[4194304];
    bf16x4 a3 = *(const bf16x4*)&base[6291456];
    bf16x4 r;
#pragma unroll
    for (int i = 0; i < 4; i++)
        r[i] = (__bf16)(((float)a0[i] + (float)a1[i] +
                         (float)a2[i] + (float)a3[i]) * li);
    *(bf16x4*)&acat[(size_t)(b * Ss + q) * 512 + h * 32 + dg * 4] = r;
}

// ---------------------------------------------------------------------------
extern "C" void kernel_launch(void* const* d_in, const int* in_sizes, int n_in,
                              void* d_out, int out_size, void* d_ws, size_t ws_size,
                              hipStream_t stream)
{
    const float* x      = (const float*)d_in[0];
    const float* g_in_w = (const float*)d_in[1];
    const float* g_in_b = (const float*)d_in[2];
    const float* g_out_w= (const float*)d_in[3];
    const float* g_out_b= (const float*)d_in[4];
    const float* t_in_w = (const float*)d_in[5];
    const float* t_in_b = (const float*)d_in[6];
    const float* t_out_w= (const float*)d_in[7];
    const float* t_out_b= (const float*)d_in[8];
    const float* fus_w1 = (const float*)d_in[9];
    const float* fus_b1 = (const float*)d_in[10];
    const float* fus_w2 = (const float*)d_in[11];
    const float* fus_b2 = (const float*)d_in[12];
    const float* ffn_w1 = (const float*)d_in[13];
    const float* ffn_b1 = (const float*)d_in[14];
    const float* ffn_w2 = (const float*)d_in[15];
    const float* ffn_b2 = (const float*)d_in[16];
    const float* gn_g   = (const float*)d_in[17];
    const float* gn_b   = (const float*)d_in[18];
    const float* fn_g   = (const float*)d_in[19];
    const float* fn_b   = (const float*)d_in[20];
    float* out = (float*)d_out;
    float* ws  = (float*)d_ws;

    // ws layout in f32 slots (R8 layout)
    __bf16* xb     = (__bf16*)(ws);                 // [0, 1048576)
    __bf16* wb     = (__bf16*)(ws + 1048576);       // [1048576, 1638400)
    __bf16* qkvgl  = (__bf16*)(ws + 1638400);       // [1638400, 7929856)  8192x1536
    __bf16* acat   = (__bf16*)(ws + 7929856);       // [7929856, 10027008) 8192x512
    __bf16* fcomb  = (__bf16*)(ws + 10027008);      // [10027008, 12124160) 8192x512
    __bf16* h1     = (__bf16*)(ws + 12124160);      // [12124160, 14221312) 8192x512
    float*  x2     = ws + 16318464;                 // [16318464, 18415616) fp32
    __bf16* x2b    = (__bf16*)(ws + 18415616);      // [18415616, 19464192)
    __bf16* h2     = h1;                            // reuse
    // attention partials: live only between attn_fused and attn_combine.
    __bf16* Op = (__bf16*)(ws + 10027008);          // 4x65536x32 bf16 over fcomb+h1
    float*  Lp = ws + 18415616;                     // 4x65536 fp32 over x2b

    __bf16* w_gin  = wb;              // [1536x256] combined (g rows 0-767, t 768-1535)
    __bf16* w_gout = wb + 393216;
    __bf16* w_tout = wb + 458752;
    __bf16* w_f1   = wb + 524288;
    __bf16* w_f2   = wb + 786432;
    __bf16* w_n1   = wb + 917504;
    __bf16* w_n2   = wb + 1048576;

    CvtArgs ca;
    ca.src[0] = x;      ca.dst[0] = xb;
    ca.src[1] = g_in_w; ca.dst[1] = w_gin;
    ca.src[2] = t_in_w; ca.dst[2] = w_gin + 196608;
    ca.src[3] = g_out_w;ca.dst[3] = w_gout;
    ca.src[4] = t_out_w;ca.dst[4] = w_tout;
    ca.src[5] = fus_w1; ca.dst[5] = w_f1;
    ca.src[6] = fus_w2; ca.dst[6] = w_f2;
    ca.src[7] = ffn_w1; ca.dst[7] = w_n1;
    ca.src[8] = ffn_w2; ca.dst[8] = w_n2;
    int st[10] = {0, 1024, 1120, 1216, 1248, 1280, 1408, 1472, 1536, 1600};
    for (int i = 0; i < 10; i++) ca.start[i] = st[i];

    convert_all<<<dim3(1600), 256, 0, stream>>>(ca);

    // Combined QKV projection: M=8192, N=1536, K=256 -> qkvgl (128x128 tiles)
    gemm128<<<dim3(12, 64), 256, 0, stream>>>(
        xb, w_gin, g_in_b, t_in_b, 768, qkvgl, 256, QSTR);
    // Global attention partials split-K x4 (blocks 0-1023) + local (1024-1535)
    attn_fused<<<dim3(1536), 512, 0, stream>>>(qkvgl, Op, Lp, acat);
    // Combine partials -> acat cols 0-255
    attn_combine<<<dim3(2048), 256, 0, stream>>>(Op, Lp, acat);
    // Fused output projections (both halves in one launch) into fcomb
    gemm_mid<false, true><<<dim3(8, 128), 256, 0, stream>>>(
        acat, w_gout, g_out_b, w_tout, t_out_b, 4, 256, 256, fcomb, 512, 256, 512);
    // Fusion MLP layer 1
    gemm_mid<true,  true><<<dim3(8, 128), 256, 0, stream>>>(
        fcomb, w_f1, fus_b1, w_f1, fus_b1, 1 << 30, 0, 0, h1, 512, 512, 512);
    // Fusion MLP layer 2 + residual(x) + LN1 -> x2 (fp32) and x2b (bf16)
    gemm_ln<true><<<dim3(512), 256, 0, stream>>>(
        h1, w_f2, fus_b2, x, gn_g, gn_b, x2, x2b);
    // FFN layer 1
    gemm_mid<true,  true><<<dim3(8, 128), 256, 0, stream>>>(
        x2b, w_n1, ffn_b1, w_n1, ffn_b1, 1 << 30, 0, 0, h2, 256, 256, 512);
    // FFN layer 2 + residual(x2) + LN2 -> out
    gemm_ln<false><<<dim3(512), 256, 0, stream>>>(
        h2, w_n2, ffn_b2, x2, fn_g, fn_b, out, nullptr);
}